// Round 1
// baseline (12698.513 us; speedup 1.0000x reference)
//
#include <hip/hip_runtime.h>
#include <hip/hip_bf16.h>

typedef __bf16 bf16x8 __attribute__((ext_vector_type(8)));
typedef float  f32x4  __attribute__((ext_vector_type(4)));

#define LR_C 0.001f

__device__ __forceinline__ float sigf(float x){ return 1.0f/(1.0f + __expf(-x)); }

__device__ __forceinline__ void gload_lds16(const void* g, void* l){
  __builtin_amdgcn_global_load_lds(
      (const __attribute__((address_space(1))) void*)g,
      (__attribute__((address_space(3))) void*)l, 16, 0, 0);
}

// ---------------- prep kernels (one-time per launch) ----------------

__global__ void k_cvt_bf16(__hip_bfloat16* dst, const float* src, int n){
  int i = blockIdx.x*256 + threadIdx.x;
  if (i < n) dst[i] = __float2bfloat16(src[i]);
}

// dst[r][c] (stride cd) = c<cs ? src[r][c] : 0
__global__ void k_cvt_pad(__hip_bfloat16* dst, const float* src, int rows, int cs, int cd){
  int i = blockIdx.x*256 + threadIdx.x;
  if (i >= rows*cd) return;
  int r = i / cd, c = i % cd;
  float v = (c < cs) ? src[r*cs + c] : 0.0f;
  dst[i] = __float2bfloat16(v);
}

// dst[n][j] (stride dstride, n<sc, j padded to dstride with 0) = src[j][n] (src sr x sc)
__global__ void k_transpose(__hip_bfloat16* dst, const float* src, int sr, int sc, int dstride){
  int i = blockIdx.x*256 + threadIdx.x;
  if (i >= sc*dstride) return;
  int n = i / dstride, j = i % dstride;
  float v = (j < sr) ? src[j*sc + n] : 0.0f;
  dst[i] = __float2bfloat16(v);
}

__global__ void k_init_state(float* sf, __hip_bfloat16* A, const float* s, int n){
  int i = blockIdx.x*256 + threadIdx.x;
  if (i >= n) return;
  float v = s[i];
  sf[i] = v;
  A[i] = __float2bfloat16(sigf(v));
}

// s3: 8192x10 -> s3f (stride 10), A3 (stride 32, cols 10..31 = 0)
__global__ void k_init_s3(float* s3f, __hip_bfloat16* A3, const float* s3){
  int i = blockIdx.x*256 + threadIdx.x;
  if (i >= 8192*32) return;
  int b = i >> 5, c = i & 31;
  if (c < 10){
    float v = s3[b*10 + c];
    s3f[b*10 + c] = v;
    A3[i] = __float2bfloat16(sigf(v));
  } else {
    A3[i] = __float2bfloat16(0.0f);
  }
}

__global__ void k_zero_bf16(__hip_bfloat16* p, int n){
  int i = blockIdx.x*256 + threadIdx.x;
  if (i < n) p[i] = __float2bfloat16(0.0f);
}

__global__ void k_copy_f32(float* dst, const float* src, int n){
  int i = blockIdx.x*256 + threadIdx.x;
  if (i < n) dst[i] = src[i];
}

// ---------------- main NT GEMM: C = A(MxK) * B(NxK)^T, fused epilogues ----------------
// EP==0 (PRED): e = f_in - acc -> bf_out ; if f_out: f_out = acc (p0 final)
// EP==1 (UPD):  a=bf_out(old), e=e_in, s=f_in; sn = s + LR*(-e + a*(1-a)*acc);
//               f_out = sn; bf_out = bf16(sig(sn))
// EP==2 (UPD3): same without -e term.
template<int EP>
__global__ __launch_bounds__(256)
void gemm_nt(const ushort* __restrict__ A, const ushort* __restrict__ B,
             int N, int K, int lda, int ldb,
             const float* f_in, int fi_stride,
             float* f_out, int fo_stride,
             const __hip_bfloat16* __restrict__ e_in, int e_stride,
             __hip_bfloat16* bf_out, int bfo_stride)
{
  __shared__ __align__(16) ushort As[128*32];
  __shared__ __align__(16) ushort Bs[128*32];

  const int t    = threadIdx.x;
  const int brow = blockIdx.y * 128;
  const int bcol = blockIdx.x * 128;
  const int w    = t >> 6;
  const int lane = t & 63;
  const int wr   = (w >> 1) * 64;
  const int wc   = (w & 1) * 64;
  const int fr   = lane & 15;
  const int ks   = (lane >> 4) * 8;

  f32x4 acc[4][4];
#pragma unroll
  for (int m=0;m<4;m++)
#pragma unroll
    for (int n=0;n<4;n++){ acc[m][n][0]=0.f; acc[m][n][1]=0.f; acc[m][n][2]=0.f; acc[m][n][3]=0.f; }

  // staging geometry: each instr loads 64 rows x 32 cols (256 thr x 16B)
  const int arow = t >> 2;
  const int acol = (t & 3) * 8;
  const ushort* gA  = A + (size_t)(brow + arow) * lda + acol;
  const ushort* gA2 = gA + (size_t)64 * lda;
  int rb  = bcol + arow;      if (rb  > N-1) rb  = N-1;
  int rb2 = bcol + 64 + arow; if (rb2 > N-1) rb2 = N-1;
  const ushort* gB  = B + (size_t)rb  * ldb + acol;
  const ushort* gB2 = B + (size_t)rb2 * ldb + acol;

  // wave-uniform LDS bases (global_load_lds: base + lane*16B)
  ushort* ldsA  = &As[w * 512];
  ushort* ldsA2 = &As[2048 + w * 512];
  ushort* ldsB  = &Bs[w * 512];
  ushort* ldsB2 = &Bs[2048 + w * 512];

  for (int k0 = 0; k0 < K; k0 += 32){
    gload_lds16(gA  + k0, ldsA);
    gload_lds16(gA2 + k0, ldsA2);
    gload_lds16(gB  + k0, ldsB);
    gload_lds16(gB2 + k0, ldsB2);
    __syncthreads();

    bf16x8 af[4], bfv[4];
#pragma unroll
    for (int m=0;m<4;m++) af[m]  = *(const bf16x8*)&As[(wr + m*16 + fr)*32 + ks];
#pragma unroll
    for (int n=0;n<4;n++) bfv[n] = *(const bf16x8*)&Bs[(wc + n*16 + fr)*32 + ks];
#pragma unroll
    for (int m=0;m<4;m++)
#pragma unroll
      for (int n=0;n<4;n++)
        acc[m][n] = __builtin_amdgcn_mfma_f32_16x16x32_bf16(af[m], bfv[n], acc[m][n], 0, 0, 0);
    __syncthreads();
  }

  // epilogue: frag (m,n): row = brow+wr+m*16+(lane>>4)*4+j ; col = bcol+wc+n*16+fr
  const int orow0 = brow + wr + (lane >> 4) * 4;
  const int ocol0 = bcol + wc + fr;
#pragma unroll
  for (int m=0;m<4;m++){
#pragma unroll
    for (int n=0;n<4;n++){
      int col = ocol0 + n*16;
      if (col >= N) continue;
#pragma unroll
      for (int j=0;j<4;j++){
        int row = orow0 + m*16 + j;
        float g = acc[m][n][j];
        if (EP == 0){
          float e = f_in[(size_t)row*fi_stride + col] - g;
          bf_out[(size_t)row*bfo_stride + col] = __float2bfloat16(e);
          if (f_out) f_out[(size_t)row*fo_stride + col] = g;
        } else if (EP == 1){
          size_t oi = (size_t)row*bfo_stride + col;
          float a = __bfloat162float(bf_out[oi]);
          float e = __bfloat162float(e_in[(size_t)row*e_stride + col]);
          float s = f_in[(size_t)row*fi_stride + col];
          float sn = s + LR_C*(-e + a*(1.0f-a)*g);
          f_out[(size_t)row*fo_stride + col] = sn;
          bf_out[oi] = __float2bfloat16(sigf(sn));
        } else {
          size_t oi = (size_t)row*bfo_stride + col;
          float a = __bfloat162float(bf_out[oi]);
          float s = f_in[(size_t)row*fi_stride + col];
          float sn = s + LR_C*(a*(1.0f-a)*g);
          f_out[(size_t)row*fo_stride + col] = sn;
          bf_out[oi] = __float2bfloat16(sigf(sn));
        }
      }
    }
  }
}

// ---------------- host orchestration ----------------

extern "C" void kernel_launch(void* const* d_in, const int* in_sizes, int n_in,
                              void* d_out, int out_size, void* d_ws, size_t ws_size,
                              hipStream_t stream) {
  const float* input = (const float*)d_in[0];
  const float* s1    = (const float*)d_in[1];
  const float* s2    = (const float*)d_in[2];
  const float* s3    = (const float*)d_in[3];
  const float* W1    = (const float*)d_in[4];
  const float* W2    = (const float*)d_in[5];
  const float* W3    = (const float*)d_in[6];
  float* out = (float*)d_out;

  char* ws = (char*)d_ws;
  size_t off = 0;
  auto take = [&](size_t bytes)->char*{
    char* p = ws + off;
    off = (off + bytes + 255) & ~(size_t)255;
    return p;
  };

  float* s1f = (float*)take(8192ull*1024*4);
  float* s2f = (float*)take(8192ull*512*4);
  float* s3f = (float*)take(8192ull*10*4);
  __hip_bfloat16* A1  = (__hip_bfloat16*)take(8192ull*1024*2);
  __hip_bfloat16* A2  = (__hip_bfloat16*)take(8192ull*512*2);
  __hip_bfloat16* A3  = (__hip_bfloat16*)take(8192ull*32*2);
  __hip_bfloat16* e0  = (__hip_bfloat16*)take(8192ull*800*2);
  __hip_bfloat16* e1  = (__hip_bfloat16*)take(8192ull*1024*2);
  __hip_bfloat16* e2  = (__hip_bfloat16*)take(8192ull*512*2);
  __hip_bfloat16* W1b = (__hip_bfloat16*)take(784ull*1024*2);
  __hip_bfloat16* W2b = (__hip_bfloat16*)take(1024ull*512*2);
  __hip_bfloat16* W3b = (__hip_bfloat16*)take(512ull*32*2);
  __hip_bfloat16* W1T = (__hip_bfloat16*)take(1024ull*800*2);
  __hip_bfloat16* W2T = (__hip_bfloat16*)take(512ull*1024*2);
  __hip_bfloat16* W3T = (__hip_bfloat16*)take(16ull*512*2);

  auto cdiv = [](int a, int b){ return (a + b - 1) / b; };

  // --- prep (every call: d_ws is poisoned before timing) ---
  k_cvt_bf16 <<<cdiv(784*1024,256),256,0,stream>>>(W1b, W1, 784*1024);
  k_cvt_bf16 <<<cdiv(1024*512,256),256,0,stream>>>(W2b, W2, 1024*512);
  k_cvt_pad  <<<cdiv(512*32,256),256,0,stream>>>(W3b, W3, 512, 10, 32);
  k_transpose<<<cdiv(1024*800,256),256,0,stream>>>(W1T, W1, 784, 1024, 800);
  k_transpose<<<cdiv(512*1024,256),256,0,stream>>>(W2T, W2, 1024, 512, 1024);
  k_transpose<<<cdiv(10*512,256),256,0,stream>>>(W3T, W3, 512, 10, 512);
  k_init_state<<<cdiv(8192*1024,256),256,0,stream>>>(s1f, A1, s1, 8192*1024);
  k_init_state<<<cdiv(8192*512,256),256,0,stream>>>(s2f, A2, s2, 8192*512);
  k_init_s3  <<<cdiv(8192*32,256),256,0,stream>>>(s3f, A3, s3);
  k_zero_bf16<<<cdiv(8192*800,256),256,0,stream>>>(e0, 8192*800);   // zeros K-pad cols 784..799

  // --- 60 cycles ---
  for (int c = 0; c < 60; ++c){
    float* p0_dst = (c == 59) ? (out + 8192*10) : nullptr;

    // P1: e0 = input - sig(s1)@W1^T   (M=8192,N=784,K=1024)
    gemm_nt<0><<<dim3(7,64),256,0,stream>>>(
        (const ushort*)A1, (const ushort*)W1b, 784, 1024, 1024, 1024,
        input, 784, p0_dst, 784, nullptr, 0, e0, 800);
    // P2: e1 = s1 - sig(s2)@W2^T      (N=1024,K=512)
    gemm_nt<0><<<dim3(8,64),256,0,stream>>>(
        (const ushort*)A2, (const ushort*)W2b, 1024, 512, 512, 512,
        s1f, 1024, nullptr, 0, nullptr, 0, e1, 1024);
    // P3: e2 = s2 - sig(s3)@W3^T      (N=512,K=32 padded from 10)
    gemm_nt<0><<<dim3(4,64),256,0,stream>>>(
        (const ushort*)A3, (const ushort*)W3b, 512, 32, 32, 32,
        s2f, 512, nullptr, 0, nullptr, 0, e2, 512);
    // U1: s1 += LR*(-e1 + sig'(s1)*(e0@W1))   (N=1024,K=800 padded from 784)
    gemm_nt<1><<<dim3(8,64),256,0,stream>>>(
        (const ushort*)e0, (const ushort*)W1T, 1024, 800, 800, 800,
        s1f, 1024, s1f, 1024, e1, 1024, A1, 1024);
    // U2: s2 += LR*(-e2 + sig'(s2)*(e1@W2))   (N=512,K=1024)
    gemm_nt<1><<<dim3(4,64),256,0,stream>>>(
        (const ushort*)e1, (const ushort*)W2T, 512, 1024, 1024, 1024,
        s2f, 512, s2f, 512, e2, 512, A2, 512);
    // U3: s3 += LR*(sig'(s3)*(e2@W3))         (N=10,K=512)
    gemm_nt<2><<<dim3(1,64),256,0,stream>>>(
        (const ushort*)e2, (const ushort*)W3T, 10, 512, 512, 512,
        s3f, 10, s3f, 10, nullptr, 0, A3, 32);
  }

  // s3 -> d_out[0 : 81920]
  k_copy_f32<<<cdiv(8192*10,256),256,0,stream>>>(out, s3f, 8192*10);
}

// Round 2
// 8749.313 us; speedup vs baseline: 1.4514x; 1.4514x over previous
//
#include <hip/hip_runtime.h>
#include <hip/hip_bf16.h>

typedef __bf16 bf16x8 __attribute__((ext_vector_type(8)));
typedef float  f32x4  __attribute__((ext_vector_type(4)));

#define LR_C 0.001f

__device__ __forceinline__ float sigf(float x){ return 1.0f/(1.0f + __expf(-x)); }

__device__ __forceinline__ void gload_lds16(const void* g, void* l){
  __builtin_amdgcn_global_load_lds(
      (const __attribute__((address_space(1))) void*)g,
      (__attribute__((address_space(3))) void*)l, 16, 0, 0);
}

// ---------------- prep kernels (once per launch) ----------------

__global__ void k_cvt_bf16(__hip_bfloat16* dst, const float* src, int n){
  int i = blockIdx.x*256 + threadIdx.x;
  if (i < n) dst[i] = __float2bfloat16(src[i]);
}

__global__ void k_cvt_pad(__hip_bfloat16* dst, const float* src, int rows, int cs, int cd){
  int i = blockIdx.x*256 + threadIdx.x;
  if (i >= rows*cd) return;
  int r = i / cd, c = i % cd;
  float v = (c < cs) ? src[r*cs + c] : 0.0f;
  dst[i] = __float2bfloat16(v);
}

__global__ void k_transpose(__hip_bfloat16* dst, const float* src, int sr, int sc, int dstride){
  int i = blockIdx.x*256 + threadIdx.x;
  if (i >= sc*dstride) return;
  int n = i / dstride, j = i % dstride;
  float v = (j < sr) ? src[j*sc + n] : 0.0f;
  dst[i] = __float2bfloat16(v);
}

__global__ void k_init_state(float* sf, __hip_bfloat16* A, const float* s, int n){
  int i = blockIdx.x*256 + threadIdx.x;
  if (i >= n) return;
  float v = s[i];
  sf[i] = v;
  A[i] = __float2bfloat16(sigf(v));
}

__global__ void k_init_s3(float* s3f, __hip_bfloat16* A3, const float* s3){
  int i = blockIdx.x*256 + threadIdx.x;
  if (i >= 8192*32) return;
  int b = i >> 5, c = i & 31;
  if (c < 10){
    float v = s3[b*10 + c];
    s3f[b*10 + c] = v;
    A3[i] = __float2bfloat16(sigf(v));
  } else {
    A3[i] = __float2bfloat16(0.0f);
  }
}

__global__ void k_zero_bf16(__hip_bfloat16* p, int n){
  int i = blockIdx.x*256 + threadIdx.x;
  if (i < n) p[i] = __float2bfloat16(0.0f);
}

__global__ void k_copy_f32(float* dst, const float* src, int n){
  int i = blockIdx.x*256 + threadIdx.x;
  if (i < n) dst[i] = src[i];
}

// ---------------- fused NT GEMM core ----------------
// C = A(MxK,bf16) * B(NxK,bf16)^T
// EP==0 (PRED): e = f_in - acc -> bf_out ; if f_out: f_out = acc
// EP==1 (UPD):  s=f_in; a=sig(s); sn = s + LR*(-e_in + a*(1-a)*acc);
//               f_out=sn; bf_out=bf16(sig(sn))
// EP==2 (UPD3): same without -e term.

struct Op {
  const ushort* A; const ushort* B;
  int N, K, lda, ldb;
  const float* f_in; int fi;
  float* f_out; int fo;
  const __hip_bfloat16* e_in; int es;
  __hip_bfloat16* bf_out; int bfo;
  int nbx;
};

template<int EP>
__device__ __forceinline__ void gemm_core(const Op& o, int lid, ushort* As, ushort* Bs){
  const int bx = lid % o.nbx;
  const int by = lid / o.nbx;
  const int brow = by * 128;
  const int bcol = bx * 128;

  const int t    = threadIdx.x;
  const int w    = t >> 6;
  const int lane = t & 63;
  const int wr   = (w >> 1) * 64;
  const int wc   = (w & 1) * 64;
  const int fr   = lane & 15;
  const int ks   = (lane >> 4) * 8;

  f32x4 acc[4][4];
#pragma unroll
  for (int m=0;m<4;m++)
#pragma unroll
    for (int n=0;n<4;n++){ acc[m][n][0]=0.f; acc[m][n][1]=0.f; acc[m][n][2]=0.f; acc[m][n][3]=0.f; }

  const int arow = t >> 2;
  const int acol = (t & 3) * 8;
  const ushort* gA  = o.A + (size_t)(brow + arow) * o.lda + acol;
  const ushort* gA2 = gA + (size_t)64 * o.lda;
  int rb  = bcol + arow;      if (rb  > o.N-1) rb  = o.N-1;
  int rb2 = bcol + 64 + arow; if (rb2 > o.N-1) rb2 = o.N-1;
  const ushort* gB  = o.B + (size_t)rb  * o.ldb + acol;
  const ushort* gB2 = o.B + (size_t)rb2 * o.ldb + acol;

  ushort* ldsA  = &As[w * 512];
  ushort* ldsA2 = &As[2048 + w * 512];
  ushort* ldsB  = &Bs[w * 512];
  ushort* ldsB2 = &Bs[2048 + w * 512];

  for (int k0 = 0; k0 < o.K; k0 += 32){
    gload_lds16(gA  + k0, ldsA);
    gload_lds16(gA2 + k0, ldsA2);
    gload_lds16(gB  + k0, ldsB);
    gload_lds16(gB2 + k0, ldsB2);
    __syncthreads();

    bf16x8 af[4], bfv[4];
#pragma unroll
    for (int m=0;m<4;m++) af[m]  = *(const bf16x8*)&As[(wr + m*16 + fr)*32 + ks];
#pragma unroll
    for (int n=0;n<4;n++) bfv[n] = *(const bf16x8*)&Bs[(wc + n*16 + fr)*32 + ks];
#pragma unroll
    for (int m=0;m<4;m++)
#pragma unroll
      for (int n=0;n<4;n++)
        acc[m][n] = __builtin_amdgcn_mfma_f32_16x16x32_bf16(af[m], bfv[n], acc[m][n], 0, 0, 0);
    __syncthreads();
  }

  const int orow0 = brow + wr + (lane >> 4) * 4;
  const int ocol0 = bcol + wc + fr;
#pragma unroll
  for (int m=0;m<4;m++){
#pragma unroll
    for (int n=0;n<4;n++){
      int col = ocol0 + n*16;
      if (col >= o.N) continue;
#pragma unroll
      for (int j=0;j<4;j++){
        int row = orow0 + m*16 + j;
        float g = acc[m][n][j];
        if (EP == 0){
          float e = o.f_in[(size_t)row*o.fi + col] - g;
          o.bf_out[(size_t)row*o.bfo + col] = __float2bfloat16(e);
          if (o.f_out) o.f_out[(size_t)row*o.fo + col] = g;
        } else {
          float s = o.f_in[(size_t)row*o.fi + col];
          float a = sigf(s);
          float upd = a*(1.0f-a)*g;
          if (EP == 1) upd -= __bfloat162float(o.e_in[(size_t)row*o.es + col]);
          float sn = s + LR_C*upd;
          o.f_out[(size_t)row*o.fo + col] = sn;
          o.bf_out[(size_t)row*o.bfo + col] = __float2bfloat16(sigf(sn));
        }
      }
    }
  }
}

template<int EPa,int EPb,int EPc>
__global__ __launch_bounds__(256)
void fused3(Op oa, Op ob, Op oc, int na, int nab){
  __shared__ __align__(16) ushort As[128*32];
  __shared__ __align__(16) ushort Bs[128*32];
  int bid = blockIdx.x;
  if (bid < na)       gemm_core<EPa>(oa, bid,       As, Bs);
  else if (bid < nab) gemm_core<EPb>(ob, bid - na,  As, Bs);
  else                gemm_core<EPc>(oc, bid - nab, As, Bs);
}

// ---------------- host orchestration ----------------

extern "C" void kernel_launch(void* const* d_in, const int* in_sizes, int n_in,
                              void* d_out, int out_size, void* d_ws, size_t ws_size,
                              hipStream_t stream) {
  const float* input = (const float*)d_in[0];
  const float* s1    = (const float*)d_in[1];
  const float* s2    = (const float*)d_in[2];
  const float* s3    = (const float*)d_in[3];
  const float* W1    = (const float*)d_in[4];
  const float* W2    = (const float*)d_in[5];
  const float* W3    = (const float*)d_in[6];
  float* out = (float*)d_out;

  char* ws = (char*)d_ws;
  size_t off = 0;
  auto take = [&](size_t bytes)->char*{
    char* p = ws + off;
    off = (off + bytes + 255) & ~(size_t)255;
    return p;
  };

  float* s1f = (float*)take(8192ull*1024*4);
  float* s2f = (float*)take(8192ull*512*4);
  float* s3f = (float*)take(8192ull*10*4);
  __hip_bfloat16* A1  = (__hip_bfloat16*)take(8192ull*1024*2);
  __hip_bfloat16* A2  = (__hip_bfloat16*)take(8192ull*512*2);
  __hip_bfloat16* A3  = (__hip_bfloat16*)take(8192ull*32*2);
  __hip_bfloat16* e0  = (__hip_bfloat16*)take(8192ull*800*2);
  __hip_bfloat16* e1  = (__hip_bfloat16*)take(8192ull*1024*2);
  __hip_bfloat16* e2  = (__hip_bfloat16*)take(8192ull*512*2);
  __hip_bfloat16* W1b = (__hip_bfloat16*)take(784ull*1024*2);
  __hip_bfloat16* W2b = (__hip_bfloat16*)take(1024ull*512*2);
  __hip_bfloat16* W3b = (__hip_bfloat16*)take(512ull*32*2);
  __hip_bfloat16* W1T = (__hip_bfloat16*)take(1024ull*800*2);
  __hip_bfloat16* W2T = (__hip_bfloat16*)take(512ull*1024*2);
  __hip_bfloat16* W3T = (__hip_bfloat16*)take(16ull*512*2);

  auto cdiv = [](int a, int b){ return (a + b - 1) / b; };

  // --- prep ---
  k_cvt_bf16 <<<cdiv(784*1024,256),256,0,stream>>>(W1b, W1, 784*1024);
  k_cvt_bf16 <<<cdiv(1024*512,256),256,0,stream>>>(W2b, W2, 1024*512);
  k_cvt_pad  <<<cdiv(512*32,256),256,0,stream>>>(W3b, W3, 512, 10, 32);
  k_transpose<<<cdiv(1024*800,256),256,0,stream>>>(W1T, W1, 784, 1024, 800);
  k_transpose<<<cdiv(512*1024,256),256,0,stream>>>(W2T, W2, 1024, 512, 1024);
  k_transpose<<<cdiv(10*512,256),256,0,stream>>>(W3T, W3, 512, 10, 512);
  k_init_state<<<cdiv(8192*1024,256),256,0,stream>>>(s1f, A1, s1, 8192*1024);
  k_init_state<<<cdiv(8192*512,256),256,0,stream>>>(s2f, A2, s2, 8192*512);
  k_init_s3  <<<cdiv(8192*32,256),256,0,stream>>>(s3f, A3, s3);
  k_zero_bf16<<<cdiv(8192*800,256),256,0,stream>>>(e0, 8192*800);

  // --- per-cycle Op descriptors (only p0_dst varies) ---
  Op P1{(const ushort*)A1, (const ushort*)W1b, 784, 1024, 1024, 1024,
        input, 784, nullptr, 784, nullptr, 0, e0, 800, 7};
  Op P2{(const ushort*)A2, (const ushort*)W2b, 1024, 512, 512, 512,
        s1f, 1024, nullptr, 0, nullptr, 0, e1, 1024, 8};
  Op P3{(const ushort*)A3, (const ushort*)W3b, 512, 32, 32, 32,
        s2f, 512, nullptr, 0, nullptr, 0, e2, 512, 4};
  Op U1{(const ushort*)e0, (const ushort*)W1T, 1024, 800, 800, 800,
        s1f, 1024, s1f, 1024, e1, 1024, A1, 1024, 8};
  Op U2{(const ushort*)e1, (const ushort*)W2T, 512, 1024, 1024, 1024,
        s2f, 512, s2f, 512, e2, 512, A2, 512, 4};
  Op U3{(const ushort*)e2, (const ushort*)W3T, 10, 512, 512, 512,
        s3f, 10, s3f, 10, nullptr, 0, A3, 32, 1};

  const int nP1 = 7*64, nP2 = 8*64, nP3 = 4*64;   // 448, 512, 256 -> 1216
  const int nU1 = 8*64, nU2 = 4*64, nU3 = 1*64;   // 512, 256, 64  -> 832

  for (int c = 0; c < 60; ++c){
    P1.f_out = (c == 59) ? (out + 8192*10) : nullptr;
    fused3<0,0,0><<<nP1+nP2+nP3, 256, 0, stream>>>(P1, P2, P3, nP1, nP1+nP2);
    fused3<1,1,2><<<nU1+nU2+nU3, 256, 0, stream>>>(U1, U2, U3, nU1, nU1+nU2);
  }

  k_copy_f32<<<cdiv(8192*10,256),256,0,stream>>>(out, s3f, 8192*10);
}